// Round 8
// baseline (158.325 us; speedup 1.0000x reference)
//
#include <hip/hip_runtime.h>

#define LAMBDA_COORD 5.0f
#define LAMBDA_NOOBJ 0.5f

constexpr int Bn = 64;       // batch
constexpr int An = 10647;    // anchors
constexpr int Cn = 9;        // classes
constexpr int Gn = 50;       // gt boxes
constexpr int PRED_ROW = 5 + Cn;        // 14 floats per anchor row
constexpr int S  = 16;                  // anchor splits
constexpr int AC = (An + S - 1) / S;    // 666 anchors per split
constexpr int ACP = 768;                // 3*256: exact 3 staging slots/thread
constexpr int GTW = 7;                  // GTs per wave per pass (4*7=28; 2 passes)

// ROUND 8 = ROUND 6 KERNELS, with k1 launched 3x (idempotent) as a
// DIAGNOSTIC: total - 103.4 ≈ 2*k1_warm. k1 is a pure function of the
// inputs, so repeated launches write identical values (capture-safe).

// ws layout:
//   partials : Bn*Gn*S float2 (score, idx-as-bits)  = 409600 B
//   bcepart  : Bn*S floats                           = 4096 B
//   per_img  : Bn floats                             = 256 B

__global__ __launch_bounds__(256, 4) void yolo_k1(
    const float* __restrict__ pred,     // [B, A, 14]
    const float* __restrict__ bboxes,   // [B, G, 4]
    float2* __restrict__ partials,      // [B, G, S]
    float* __restrict__ bcepart)        // [B, S]
{
    const int s = blockIdx.x;
    const int b = blockIdx.y;
    const int a0 = s * AC;
    const int n  = min(AC, An - a0);    // 666 (657 for last split)

    __shared__ float4 sbox[ACP];  // x1,y1,x2,y2
    __shared__ float  sap[ACP];   // area_p
    __shared__ float  sred[4];

    const int tid  = threadIdx.x;
    const int wave = tid >> 6;
    const int lane = tid & 63;

    // ---- stage anchors into LDS: branch-free, all 9 loads hoisted ----
    const float* prow = pred + (size_t)b * An * PRED_ROW;
    float2 va[3], vb[3];
    float  vc[3];
    #pragma unroll
    for (int k = 0; k < 3; ++k) {
        int i   = tid + k * 256;                      // < 768 always
        int ild = min(i, n - 1);                      // clamped: load always valid
        const float* p = prow + (size_t)(a0 + ild) * PRED_ROW;
        va[k] = ((const float2*)p)[0];                // cx, cy  (8B-aligned: 56*a)
        vb[k] = ((const float2*)p)[1];                // w, h
        vc[k] = p[4];                                 // conf
    }
    float bce = 0.0f;
    #pragma unroll
    for (int k = 0; k < 3; ++k) {
        int  i     = tid + k * 256;
        bool valid = (i < n);
        float hw = 0.5f * vb[k].x, hh = 0.5f * vb[k].y;
        float x1 = va[k].x - hw, x2 = va[k].x + hw;
        float y1 = va[k].y - hh, y2 = va[k].y + hh;
        // pad sentinel: inter=0 -> never beats strict-> compare (bn>=0)
        sbox[i] = valid ? make_float4(x1, y1, x2, y2)
                        : make_float4(1e30f, 1e30f, 1e30f, 1e30f);
        sap[i]  = valid ? (x2 - x1) * (y2 - y1) : 0.0f;
        if (valid) bce -= fmaxf(__logf(1.0f - vc[k]), -100.0f);   // bce0
    }
    #pragma unroll
    for (int off = 32; off >= 1; off >>= 1) bce += __shfl_xor(bce, off, 64);
    if (lane == 0) sred[wave] = bce;

    __syncthreads();
    if (tid == 0) bcepart[b * S + s] = sred[0] + sred[1] + sred[2] + sred[3];

    const float* bb = bboxes + (size_t)b * Gn * 4;

    // ---- two passes: pass 0 -> GTs 0..27, pass 1 -> GTs 28..49 ----
    for (int pass = 0; pass < 2; ++pass) {
        const int g0 = pass * 28 + wave * GTW;
        const int ng = min(GTW, Gn - g0);   // 7,7,7,7 then 7,7,7,1

        float gx1[GTW], gy1[GTW], gx2[GTW], gy2[GTW], gc1[GTW];
        #pragma unroll
        for (int j = 0; j < GTW; ++j) {
            int g = (j < ng) ? (g0 + j) : g0;    // pad tail with duplicate GT
            float b0 = bb[g * 4 + 0], b1 = bb[g * 4 + 1];
            float b2 = bb[g * 4 + 2], b3 = bb[g * 4 + 3];
            float gcx = 0.5f * (b0 + b2), gcy = 0.5f * (b1 + b3);
            float gw = b2 - b0, gh = b3 - b1;
            gx1[j] = gcx - gw * 0.5f; gx2[j] = gcx + gw * 0.5f;
            gy1[j] = gcy - gh * 0.5f; gy2[j] = gcy + gh * 0.5f;
            gc1[j] = (gx2[j] - gx1[j]) * (gy2[j] - gy1[j]) + 1e-16f;  // area_g+eps
        }

        float bn[GTW], bd[GTW];
        int   bidx[GTW];
        #pragma unroll
        for (int j = 0; j < GTW; ++j) { bn[j] = 0.0f; bd[j] = 1.0f; bidx[j] = 0; }

        // ---- main scan: branch-free, 7 IoUs per anchor read ----
        for (int base = 0; base < ACP; base += 64) {
            int i = base + lane;
            float4 pb = sbox[i];
            float  ap = sap[i];
            int   idx = a0 + i;
            #pragma unroll
            for (int j = 0; j < GTW; ++j) {
                float iw = fminf(pb.z, gx2[j]) - fmaxf(pb.x, gx1[j]);
                float ih = fminf(pb.w, gy2[j]) - fmaxf(pb.y, gy1[j]);
                iw = fmaxf(iw, 0.0f);
                ih = fmaxf(ih, 0.0f);
                float inter = iw * ih;
                float apc   = ap + gc1[j];
                // argmax of inter/(ap+ag-inter) == argmax of inter/(ap+ag):
                // r -> r/(1+r) monotone; compare fractions by cross-multiply.
                bool take = inter * bd[j] > bn[j] * apc;  // strict >: first max
                bn[j]   = take ? inter : bn[j];
                bd[j]   = take ? apc   : bd[j];
                bidx[j] = take ? idx   : bidx[j];
            }
        }

        // ---- cross-lane argmax per GT, write partial ----
        #pragma unroll
        for (int j = 0; j < GTW; ++j) {
            if (j < ng) {
                float score = bn[j] * __builtin_amdgcn_rcpf(bd[j]); // monotone
                int   idx   = bidx[j];
                #pragma unroll
                for (int off = 1; off < 64; off <<= 1) {
                    float os = __shfl_xor(score, off, 64);
                    int   oi = __shfl_xor(idx, off, 64);
                    if (os > score) { score = os; idx = oi; }
                }
                if (lane == 0)
                    partials[((size_t)b * Gn + g0 + j) * S + s] =
                        make_float2(score, __int_as_float(idx));
            }
        }
    }
}

__global__ __launch_bounds__(64, 1) void yolo_k2(
    const float* __restrict__ pred,
    const float* __restrict__ bboxes,
    const int*  __restrict__ classes,   // [B, G]
    const float2* __restrict__ partials,
    const float* __restrict__ bcepart,
    float* __restrict__ per_img)        // [B]
{
    const int b = blockIdx.x;
    const int g = threadIdx.x;

    int cls = (g < Gn) ? classes[b * Gn + g] : -1;

    float tot0 = 0.0f;
    #pragma unroll
    for (int s = 0; s < S; ++s) tot0 += bcepart[b * S + s];  // broadcast loads

    float per_gt = 0.0f;
    int   validf = 0;
    if (g < Gn) {
        validf = (cls != -1) ? 1 : 0;

        const float2* pp = partials + ((size_t)b * Gn + g) * S;
        float2 c[S];
        #pragma unroll
        for (int s = 0; s < S; ++s) c[s] = pp[s];   // 16 parallel loads
        float best = -1.0f;
        int   bi = 0;
        #pragma unroll
        for (int s = 0; s < S; ++s)
            if (c[s].x > best) { best = c[s].x; bi = __float_as_int(c[s].y); }

        const float2* p2 = (const float2*)(pred + ((size_t)b * An + bi) * PRED_ROW);
        float2 r[7];
        #pragma unroll
        for (int q = 0; q < 7; ++q) r[q] = p2[q];   // 7 parallel loads (56 B row)
        float pcx = r[0].x, pcy = r[0].y, pw = r[1].x, ph = r[1].y, conf = r[2].x;

        const float* bbg = bboxes + ((size_t)b * Gn + g) * 4;
        float b0 = bbg[0], b1 = bbg[1], b2 = bbg[2], b3 = bbg[3];
        float gcx = 0.5f * (b0 + b2), gcy = 0.5f * (b1 + b3);
        float gw = b2 - b0, gh = b3 - b1;

        float dx = pcx - gcx, dy = pcy - gcy, dw = pw - gw, dh = ph - gh;
        float coord = LAMBDA_COORD * (dx * dx + dy * dy + dw * dw + dh * dh);

        float conf_obj = -fmaxf(__logf(conf), -100.0f);

        const float pcls[Cn] = { r[2].y, r[3].x, r[3].y, r[4].x, r[4].y,
                                 r[5].x, r[5].y, r[6].x, r[6].y };
        float clsl = 0.0f;
        #pragma unroll
        for (int c2 = 0; c2 < Cn; ++c2) {
            float pc = pcls[c2];
            float lp = fmaxf(__logf(pc), -100.0f);
            float ln = fmaxf(__logf(1.0f - pc), -100.0f);
            clsl -= (c2 == cls) ? lp : ln;
        }

        float bce0b = -fmaxf(__logf(1.0f - conf), -100.0f);
        float noobj = LAMBDA_NOOBJ * (tot0 - bce0b);

        per_gt = coord + conf_obj + clsl + noobj;
        if (!validf) per_gt = 0.0f;
    }

    float sum = per_gt;
    int   anyv = validf;
    #pragma unroll
    for (int off = 1; off < 64; off <<= 1) {
        sum  += __shfl_xor(sum, off, 64);
        anyv |= __shfl_xor(anyv, off, 64);
    }
    if (g == 0) per_img[b] = anyv ? sum : (LAMBDA_NOOBJ * tot0);
}

__global__ __launch_bounds__(64, 1) void yolo_k3(
    const float* __restrict__ per_img, float* __restrict__ out)
{
    float v = per_img[threadIdx.x];  // Bn == 64 == one wave
    #pragma unroll
    for (int off = 1; off < 64; off <<= 1) v += __shfl_xor(v, off, 64);
    if (threadIdx.x == 0) out[0] = v * (1.0f / (float)Bn);
}

extern "C" void kernel_launch(void* const* d_in, const int* in_sizes, int n_in,
                              void* d_out, int out_size, void* d_ws, size_t ws_size,
                              hipStream_t stream) {
    const float* pred    = (const float*)d_in[0];
    const float* bboxes  = (const float*)d_in[1];
    const int*   classes = (const int*)d_in[2];
    float* out = (float*)d_out;

    char* ws = (char*)d_ws;
    float2* partials = (float2*)ws;
    float*  bcepart  = (float*)(ws + (size_t)Bn * Gn * S * sizeof(float2));
    float*  per_img  = (float*)(ws + (size_t)Bn * Gn * S * sizeof(float2)
                                   + (size_t)Bn * S * sizeof(float));

    // DIAGNOSTIC: k1 launched 3x (pure function of inputs -> idempotent).
    // total_dur - 103.4us ≈ 2 * k1_warm. Same work every call; capture-safe.
    yolo_k1<<<dim3(S, Bn), 256, 0, stream>>>(pred, bboxes, partials, bcepart);
    yolo_k1<<<dim3(S, Bn), 256, 0, stream>>>(pred, bboxes, partials, bcepart);
    yolo_k1<<<dim3(S, Bn), 256, 0, stream>>>(pred, bboxes, partials, bcepart);
    yolo_k2<<<Bn, 64, 0, stream>>>(pred, bboxes, classes, partials, bcepart, per_img);
    yolo_k3<<<1, 64, 0, stream>>>(per_img, out);
}

// Round 9
// 124.859 us; speedup vs baseline: 1.2680x; 1.2680x over previous
//
#include <hip/hip_runtime.h>

#define LAMBDA_COORD 5.0f
#define LAMBDA_NOOBJ 0.5f

constexpr int Bn = 64;       // batch
constexpr int An = 10647;    // anchors
constexpr int Cn = 9;        // classes
constexpr int Gn = 50;       // gt boxes
constexpr int PRED_ROW = 5 + Cn;        // 14 floats per anchor row
constexpr int S  = 32;                  // splits: 32*64 = 2048 blocks = 8/CU
constexpr int AC = (An + S - 1) / S;    // 333 anchors per split
constexpr int ACP = ((AC + 63) / 64) * 64;  // 384 (6 scan iters/pass)
constexpr int GTW = 4;                  // GTs per wave per pass
constexpr int NPASS = 4;                // 4 waves * 4 GTs * 4 passes = 64 >= 50

// ws layout:
//   partials : Bn*Gn*S float2 (score, idx-as-bits)  = 819200 B
//   bcepart  : Bn*S floats                           = 8192 B
//   per_img  : Bn floats                             = 256 B

// Occupancy-targeted k1 (r8 diagnostic: k1 = 27.5us warm, VALU-issue ~8us,
// rest = issue starvation at 4 waves/SIMD). (256,8) caps VGPR at 64 -> 8
// waves/SIMD; GTW=4 keeps the live set ~52 regs (no spill); 2048 blocks
// fill all 256 CUs at 8 blocks/CU; no sap array (area recomputed, 3 VALU).
__global__ __launch_bounds__(256, 8) void yolo_k1(
    const float* __restrict__ pred,     // [B, A, 14]
    const float* __restrict__ bboxes,   // [B, G, 4]
    float2* __restrict__ partials,      // [B, G, S]
    float* __restrict__ bcepart)        // [B, S]
{
    const int s = blockIdx.x;
    const int b = blockIdx.y;
    const int a0 = s * AC;
    const int n  = min(AC, An - a0);    // 333 (330 for last split)

    __shared__ float4 sbox[ACP];  // x1,y1,x2,y2
    __shared__ float  sred[4];

    const int tid  = threadIdx.x;
    const int wave = tid >> 6;
    const int lane = tid & 63;

    // ---- stage anchors into LDS: slot 0 = all threads, slot 1 = tid<128 ----
    const float* prow = pred + (size_t)b * An * PRED_ROW;
    float bce = 0.0f;
    #pragma unroll
    for (int k = 0; k < 2; ++k) {
        int i = tid + k * 256;
        if (i < ACP) {                               // k=1: waves 0,1 only (uniform)
            int ild = min(i, n - 1);                 // clamped: load always valid
            const float* p = prow + (size_t)(a0 + ild) * PRED_ROW;
            float2 v0 = ((const float2*)p)[0];       // cx, cy (56*a is 8B-aligned)
            float2 v1 = ((const float2*)p)[1];       // w, h
            float conf = p[4];
            bool valid = (i < n);
            float hw = 0.5f * v1.x, hh = 0.5f * v1.y;
            float x1 = v0.x - hw, x2 = v0.x + hw;
            float y1 = v0.y - hh, y2 = v0.y + hh;
            // sentinel pad: inter always 0 -> never beats strict-> compare
            sbox[i] = valid ? make_float4(x1, y1, x2, y2)
                            : make_float4(1e30f, 1e30f, 1e30f, 1e30f);
            if (valid) bce -= fmaxf(__logf(1.0f - conf), -100.0f);   // bce0
        }
    }
    #pragma unroll
    for (int off = 32; off >= 1; off >>= 1) bce += __shfl_xor(bce, off, 64);
    if (lane == 0) sred[wave] = bce;

    __syncthreads();
    if (tid == 0) bcepart[b * S + s] = sred[0] + sred[1] + sred[2] + sred[3];

    const float* bb = bboxes + (size_t)b * Gn * 4;

    // ---- 4 passes x (4 waves x 4 GTs) = 64 GT slots covering 50 GTs ----
    for (int pass = 0; pass < NPASS; ++pass) {
        const int g0 = pass * 16 + wave * GTW;
        const int ng = max(0, min(GTW, Gn - g0));   // 4,...,4,2,0

        float gx1[GTW], gy1[GTW], gx2[GTW], gy2[GTW], gc1[GTW];
        #pragma unroll
        for (int j = 0; j < GTW; ++j) {
            int g = (j < ng) ? (g0 + j) : 0;         // pad with duplicate GT 0
            float b0 = bb[g * 4 + 0], b1 = bb[g * 4 + 1];
            float b2 = bb[g * 4 + 2], b3 = bb[g * 4 + 3];
            float gcx = 0.5f * (b0 + b2), gcy = 0.5f * (b1 + b3);
            float gw = b2 - b0, gh = b3 - b1;
            gx1[j] = gcx - gw * 0.5f; gx2[j] = gcx + gw * 0.5f;
            gy1[j] = gcy - gh * 0.5f; gy2[j] = gcy + gh * 0.5f;
            gc1[j] = (gx2[j] - gx1[j]) * (gy2[j] - gy1[j]) + 1e-16f;  // area_g+eps
        }

        float bn[GTW], bd[GTW];
        int   bidx[GTW];
        #pragma unroll
        for (int j = 0; j < GTW; ++j) { bn[j] = 0.0f; bd[j] = 1.0f; bidx[j] = 0; }

        // ---- main scan: branch-free, 4 IoUs per anchor read ----
        for (int base = 0; base < ACP; base += 64) {
            int i = base + lane;
            float4 pb = sbox[i];
            float  ap = (pb.z - pb.x) * (pb.w - pb.y);   // recompute area_p
            int   idx = a0 + i;
            #pragma unroll
            for (int j = 0; j < GTW; ++j) {
                float iw = fminf(pb.z, gx2[j]) - fmaxf(pb.x, gx1[j]);
                float ih = fminf(pb.w, gy2[j]) - fmaxf(pb.y, gy1[j]);
                iw = fmaxf(iw, 0.0f);
                ih = fmaxf(ih, 0.0f);
                float inter = iw * ih;
                float apc   = ap + gc1[j];
                // argmax of inter/(ap+ag-inter) == argmax of inter/(ap+ag):
                // r -> r/(1+r) monotone; compare fractions by cross-multiply.
                bool take = inter * bd[j] > bn[j] * apc;  // strict >: first max
                bn[j]   = take ? inter : bn[j];
                bd[j]   = take ? apc   : bd[j];
                bidx[j] = take ? idx   : bidx[j];
            }
        }

        // ---- cross-lane argmax per GT, write partial ----
        #pragma unroll
        for (int j = 0; j < GTW; ++j) {
            if (j < ng) {
                float score = bn[j] * __builtin_amdgcn_rcpf(bd[j]); // monotone
                int   idx   = bidx[j];
                #pragma unroll
                for (int off = 1; off < 64; off <<= 1) {
                    float os = __shfl_xor(score, off, 64);
                    int   oi = __shfl_xor(idx, off, 64);
                    if (os > score) { score = os; idx = oi; }
                }
                if (lane == 0)
                    partials[((size_t)b * Gn + g0 + j) * S + s] =
                        make_float2(score, __int_as_float(idx));
            }
        }
    }
}

// k2: one block per image, 64 lanes; lane g owns GT g. (64,1) removes the
// VGPR cap so the 32-partial fold + pred row issue as parallel loads.
__global__ __launch_bounds__(64, 1) void yolo_k2(
    const float* __restrict__ pred,
    const float* __restrict__ bboxes,
    const int*  __restrict__ classes,   // [B, G]
    const float2* __restrict__ partials,
    const float* __restrict__ bcepart,
    float* __restrict__ per_img)        // [B]
{
    const int b = blockIdx.x;
    const int g = threadIdx.x;

    int cls = (g < Gn) ? classes[b * Gn + g] : -1;

    float tot0 = 0.0f;
    #pragma unroll
    for (int s = 0; s < S; ++s) tot0 += bcepart[b * S + s];  // broadcast loads

    float per_gt = 0.0f;
    int   validf = 0;
    if (g < Gn) {
        validf = (cls != -1) ? 1 : 0;

        const float2* pp = partials + ((size_t)b * Gn + g) * S;
        float best = -1.0f;
        int   bi = 0;
        #pragma unroll
        for (int s = 0; s < S; ++s) {               // 32 independent loads
            float2 c = pp[s];
            if (c.x > best) { best = c.x; bi = __float_as_int(c.y); }
        }

        const float2* p2 = (const float2*)(pred + ((size_t)b * An + bi) * PRED_ROW);
        float2 r[7];
        #pragma unroll
        for (int q = 0; q < 7; ++q) r[q] = p2[q];   // 7 parallel loads (56 B row)
        float pcx = r[0].x, pcy = r[0].y, pw = r[1].x, ph = r[1].y, conf = r[2].x;

        const float* bbg = bboxes + ((size_t)b * Gn + g) * 4;
        float b0 = bbg[0], b1 = bbg[1], b2 = bbg[2], b3 = bbg[3];
        float gcx = 0.5f * (b0 + b2), gcy = 0.5f * (b1 + b3);
        float gw = b2 - b0, gh = b3 - b1;

        float dx = pcx - gcx, dy = pcy - gcy, dw = pw - gw, dh = ph - gh;
        float coord = LAMBDA_COORD * (dx * dx + dy * dy + dw * dw + dh * dh);

        float conf_obj = -fmaxf(__logf(conf), -100.0f);

        const float pcls[Cn] = { r[2].y, r[3].x, r[3].y, r[4].x, r[4].y,
                                 r[5].x, r[5].y, r[6].x, r[6].y };
        float clsl = 0.0f;
        #pragma unroll
        for (int c2 = 0; c2 < Cn; ++c2) {
            float pc = pcls[c2];
            float lp = fmaxf(__logf(pc), -100.0f);
            float ln = fmaxf(__logf(1.0f - pc), -100.0f);
            clsl -= (c2 == cls) ? lp : ln;
        }

        float bce0b = -fmaxf(__logf(1.0f - conf), -100.0f);
        float noobj = LAMBDA_NOOBJ * (tot0 - bce0b);

        per_gt = coord + conf_obj + clsl + noobj;
        if (!validf) per_gt = 0.0f;
    }

    float sum = per_gt;
    int   anyv = validf;
    #pragma unroll
    for (int off = 1; off < 64; off <<= 1) {
        sum  += __shfl_xor(sum, off, 64);
        anyv |= __shfl_xor(anyv, off, 64);
    }
    if (g == 0) per_img[b] = anyv ? sum : (LAMBDA_NOOBJ * tot0);
}

__global__ __launch_bounds__(64, 1) void yolo_k3(
    const float* __restrict__ per_img, float* __restrict__ out)
{
    float v = per_img[threadIdx.x];  // Bn == 64 == one wave
    #pragma unroll
    for (int off = 1; off < 64; off <<= 1) v += __shfl_xor(v, off, 64);
    if (threadIdx.x == 0) out[0] = v * (1.0f / (float)Bn);
}

extern "C" void kernel_launch(void* const* d_in, const int* in_sizes, int n_in,
                              void* d_out, int out_size, void* d_ws, size_t ws_size,
                              hipStream_t stream) {
    const float* pred    = (const float*)d_in[0];
    const float* bboxes  = (const float*)d_in[1];
    const int*   classes = (const int*)d_in[2];
    float* out = (float*)d_out;

    char* ws = (char*)d_ws;
    float2* partials = (float2*)ws;
    float*  bcepart  = (float*)(ws + (size_t)Bn * Gn * S * sizeof(float2));
    float*  per_img  = (float*)(ws + (size_t)Bn * Gn * S * sizeof(float2)
                                   + (size_t)Bn * S * sizeof(float));

    yolo_k1<<<dim3(S, Bn), 256, 0, stream>>>(pred, bboxes, partials, bcepart);
    yolo_k2<<<Bn, 64, 0, stream>>>(pred, bboxes, classes, partials, bcepart, per_img);
    yolo_k3<<<1, 64, 0, stream>>>(per_img, out);
}

// Round 10
// 106.995 us; speedup vs baseline: 1.4797x; 1.1670x over previous
//
#include <hip/hip_runtime.h>

#define LAMBDA_COORD 5.0f
#define LAMBDA_NOOBJ 0.5f

constexpr int Bn = 64;       // batch
constexpr int An = 10647;    // anchors
constexpr int Cn = 9;        // classes
constexpr int Gn = 50;       // gt boxes
constexpr int PRED_ROW = 5 + Cn;        // 14 floats per anchor row
constexpr int S  = 32;                  // splits: 32*64 = 2048 blocks = 8/CU
constexpr int AC = (An + S - 1) / S;    // 333 anchors per split
constexpr int ACP = ((AC + 3) / 4) * 4; // 336 = 4 * 84
constexpr int QW  = ACP / 4;            // 84 anchors per wave (serial scan)

// ws layout:
//   partials : Bn*Gn*S float2 (score, idx-as-bits)  = 819200 B
//   bcepart  : Bn*S floats                           = 8192 B
//   per_img  : Bn floats                             = 256 B

// LANE-PER-GT decomposition (r9 post-mortem: register GT-tiles spill at any
// occupancy-compatible VGPR cap — 48 MB scratch writes at (256,8)).
// Here lane g owns GT g: per-lane state is 5 consts + 3 accumulators, ~25
// live VGPRs TOTAL -> spill-proof at the 64-reg cap, 8 waves/SIMD for free.
// Anchor reads are wave-uniform LDS addresses -> HW broadcast, 0 conflicts.
__global__ __launch_bounds__(256, 8) void yolo_k1(
    const float* __restrict__ pred,     // [B, A, 14]
    const float* __restrict__ bboxes,   // [B, G, 4]
    float2* __restrict__ partials,      // [B, G, S]
    float* __restrict__ bcepart)        // [B, S]
{
    const int s = blockIdx.x;
    const int b = blockIdx.y;
    const int a0 = s * AC;
    const int n  = min(AC, An - a0);    // 333 (324 for last split)

    __shared__ float4 sbox[ACP];        // x1,y1,x2,y2 (sentinel-padded)
    __shared__ float2 sres[4][Gn];      // per-wave per-GT (score, idx-bits)
    __shared__ float  sred[4];

    const int tid  = threadIdx.x;
    const int wave = tid >> 6;
    const int lane = tid & 63;

    // ---- stage anchors into LDS + partial bce0 sum ----
    const float* prow = pred + (size_t)b * An * PRED_ROW;
    float bce = 0.0f;
    #pragma unroll
    for (int k = 0; k < 2; ++k) {
        int i = tid + k * 256;
        if (i < ACP) {                                // k=1: tid<80 only
            int ild = min(i, n - 1);                  // clamped: load always valid
            const float* p = prow + (size_t)(a0 + ild) * PRED_ROW;
            float2 v0 = ((const float2*)p)[0];        // cx, cy (56*a is 8B-aligned)
            float2 v1 = ((const float2*)p)[1];        // w, h
            float conf = p[4];
            bool valid = (i < n);
            float hw = 0.5f * v1.x, hh = 0.5f * v1.y;
            // sentinel: corners at +1e30 -> iw<0 -> inter=0 -> never selected
            sbox[i] = valid ? make_float4(v0.x - hw, v0.y - hh, v0.x + hw, v0.y + hh)
                            : make_float4(1e30f, 1e30f, 1e30f, 1e30f);
            if (valid) bce -= fmaxf(__logf(1.0f - conf), -100.0f);   // bce0
        }
    }
    #pragma unroll
    for (int off = 32; off >= 1; off >>= 1) bce += __shfl_xor(bce, off, 64);
    if (lane == 0) sred[wave] = bce;

    // ---- per-lane GT constants (lane g owns GT g; lanes >= Gn degenerate) ----
    float gx1, gy1, gx2, gy2, gc1;
    if (lane < Gn) {
        const float* bbg = bboxes + ((size_t)b * Gn + lane) * 4;
        float b0 = bbg[0], b1 = bbg[1], b2 = bbg[2], b3 = bbg[3];
        float gcx = 0.5f * (b0 + b2), gcy = 0.5f * (b1 + b3);
        float gw = b2 - b0, gh = b3 - b1;
        gx1 = gcx - gw * 0.5f; gx2 = gcx + gw * 0.5f;
        gy1 = gcy - gh * 0.5f; gy2 = gcy + gh * 0.5f;
        gc1 = (gx2 - gx1) * (gy2 - gy1) + 1e-16f;    // area_g + eps
    } else {
        gx1 = 2e30f; gx2 = -2e30f; gy1 = 2e30f; gy2 = -2e30f; gc1 = 1.0f;
    }

    __syncthreads();
    if (tid == 0) bcepart[b * S + s] = sred[0] + sred[1] + sred[2] + sred[3];

    // ---- serial scan: wave w covers anchors [w*QW, (w+1)*QW) ----
    // sbox[i] is the SAME address for all 64 lanes -> LDS broadcast read.
    float bn = 0.0f, bd = 1.0f;
    int   bidx = 0;
    const int i0 = wave * QW;
    #pragma unroll 4
    for (int q = 0; q < QW; ++q) {
        int i = i0 + q;
        float4 pb = sbox[i];
        float ap = (pb.z - pb.x) * (pb.w - pb.y);
        float iw = fminf(pb.z, gx2) - fmaxf(pb.x, gx1);
        float ih = fminf(pb.w, gy2) - fmaxf(pb.y, gy1);
        iw = fmaxf(iw, 0.0f);
        ih = fmaxf(ih, 0.0f);
        float inter = iw * ih;
        float apc   = ap + gc1;
        // argmax of inter/(ap+ag-inter) == argmax of inter/(ap+ag):
        // r -> r/(1+r) monotone; compare fractions by cross-multiply.
        bool take = inter * bd > bn * apc;   // strict >: first (lowest i) wins
        bn   = take ? inter   : bn;
        bd   = take ? apc     : bd;
        bidx = take ? (a0 + i) : bidx;
    }

    float score = bn * __builtin_amdgcn_rcpf(bd);    // monotone in iou
    if (lane < Gn) sres[wave][lane] = make_float2(score, __int_as_float(bidx));
    __syncthreads();

    // ---- fold the 4 waves' candidates (ascending wave = ascending anchor) ----
    if (wave == 0 && lane < Gn) {
        float2 c0 = sres[0][lane];
        float best = c0.x;
        int   bi   = __float_as_int(c0.y);
        #pragma unroll
        for (int w = 1; w < 4; ++w) {
            float2 c = sres[w][lane];
            if (c.x > best) { best = c.x; bi = __float_as_int(c.y); }
        }
        partials[((size_t)b * Gn + lane) * S + s] =
            make_float2(best, __int_as_float(bi));
    }
}

// k2: one block per image, 64 lanes; lane g owns GT g. (64,1) removes the
// VGPR cap so the 32-partial fold + pred row issue as parallel loads.
__global__ __launch_bounds__(64, 1) void yolo_k2(
    const float* __restrict__ pred,
    const float* __restrict__ bboxes,
    const int*  __restrict__ classes,   // [B, G]
    const float2* __restrict__ partials,
    const float* __restrict__ bcepart,
    float* __restrict__ per_img)        // [B]
{
    const int b = blockIdx.x;
    const int g = threadIdx.x;

    int cls = (g < Gn) ? classes[b * Gn + g] : -1;

    float tot0 = 0.0f;
    #pragma unroll
    for (int s = 0; s < S; ++s) tot0 += bcepart[b * S + s];  // broadcast loads

    float per_gt = 0.0f;
    int   validf = 0;
    if (g < Gn) {
        validf = (cls != -1) ? 1 : 0;

        const float2* pp = partials + ((size_t)b * Gn + g) * S;
        float best = -1.0f;
        int   bi = 0;
        #pragma unroll
        for (int s = 0; s < S; ++s) {               // 32 independent loads
            float2 c = pp[s];
            if (c.x > best) { best = c.x; bi = __float_as_int(c.y); }
        }

        const float2* p2 = (const float2*)(pred + ((size_t)b * An + bi) * PRED_ROW);
        float2 r[7];
        #pragma unroll
        for (int q = 0; q < 7; ++q) r[q] = p2[q];   // 7 parallel loads (56 B row)
        float pcx = r[0].x, pcy = r[0].y, pw = r[1].x, ph = r[1].y, conf = r[2].x;

        const float* bbg = bboxes + ((size_t)b * Gn + g) * 4;
        float b0 = bbg[0], b1 = bbg[1], b2 = bbg[2], b3 = bbg[3];
        float gcx = 0.5f * (b0 + b2), gcy = 0.5f * (b1 + b3);
        float gw = b2 - b0, gh = b3 - b1;

        float dx = pcx - gcx, dy = pcy - gcy, dw = pw - gw, dh = ph - gh;
        float coord = LAMBDA_COORD * (dx * dx + dy * dy + dw * dw + dh * dh);

        float conf_obj = -fmaxf(__logf(conf), -100.0f);

        const float pcls[Cn] = { r[2].y, r[3].x, r[3].y, r[4].x, r[4].y,
                                 r[5].x, r[5].y, r[6].x, r[6].y };
        float clsl = 0.0f;
        #pragma unroll
        for (int c2 = 0; c2 < Cn; ++c2) {
            float pc = pcls[c2];
            float lp = fmaxf(__logf(pc), -100.0f);
            float ln = fmaxf(__logf(1.0f - pc), -100.0f);
            clsl -= (c2 == cls) ? lp : ln;
        }

        float bce0b = -fmaxf(__logf(1.0f - conf), -100.0f);
        float noobj = LAMBDA_NOOBJ * (tot0 - bce0b);

        per_gt = coord + conf_obj + clsl + noobj;
        if (!validf) per_gt = 0.0f;
    }

    float sum = per_gt;
    int   anyv = validf;
    #pragma unroll
    for (int off = 1; off < 64; off <<= 1) {
        sum  += __shfl_xor(sum, off, 64);
        anyv |= __shfl_xor(anyv, off, 64);
    }
    if (g == 0) per_img[b] = anyv ? sum : (LAMBDA_NOOBJ * tot0);
}

__global__ __launch_bounds__(64, 1) void yolo_k3(
    const float* __restrict__ per_img, float* __restrict__ out)
{
    float v = per_img[threadIdx.x];  // Bn == 64 == one wave
    #pragma unroll
    for (int off = 1; off < 64; off <<= 1) v += __shfl_xor(v, off, 64);
    if (threadIdx.x == 0) out[0] = v * (1.0f / (float)Bn);
}

extern "C" void kernel_launch(void* const* d_in, const int* in_sizes, int n_in,
                              void* d_out, int out_size, void* d_ws, size_t ws_size,
                              hipStream_t stream) {
    const float* pred    = (const float*)d_in[0];
    const float* bboxes  = (const float*)d_in[1];
    const int*   classes = (const int*)d_in[2];
    float* out = (float*)d_out;

    char* ws = (char*)d_ws;
    float2* partials = (float2*)ws;
    float*  bcepart  = (float*)(ws + (size_t)Bn * Gn * S * sizeof(float2));
    float*  per_img  = (float*)(ws + (size_t)Bn * Gn * S * sizeof(float2)
                                   + (size_t)Bn * S * sizeof(float));

    yolo_k1<<<dim3(S, Bn), 256, 0, stream>>>(pred, bboxes, partials, bcepart);
    yolo_k2<<<Bn, 64, 0, stream>>>(pred, bboxes, classes, partials, bcepart, per_img);
    yolo_k3<<<1, 64, 0, stream>>>(per_img, out);
}